// Round 7
// baseline (424.113 us; speedup 1.0000x reference)
//
#include <hip/hip_runtime.h>
#include <hip/hip_fp16.h>
#include <stdint.h>

#define B_ 32
#define T_ 4096
#define P_ 512
#define W_ 128
#define NMEL 80
#define FILT 256
#define PDIM 64
#define KW 9
#define TP8 (T_ + 8)
#define MSTR 104
#define YSTR 264
#define EPS 1e-5f

typedef unsigned short u16;
typedef __attribute__((ext_vector_type(8))) short short8;
typedef __attribute__((ext_vector_type(4))) float f32x4;
typedef __attribute__((ext_vector_type(16))) float f32x16;

typedef const __attribute__((address_space(1))) uint32_t* gptr_t;
typedef __attribute__((address_space(3))) uint32_t* lptr_t;

__device__ __forceinline__ u16 f2h(float v){ return __half_as_ushort(__float2half(v)); }

#define MFMA32(accv, av, bv) \
  asm volatile("v_mfma_f32_32x32x16_f16 %0, %1, %2, %0" : "+v"(accv) : "v"(av), "v"(bv))

// stage one 16KB chunk with 256 threads (4 waves): 4 x 16B per thread
#define STAGE16K_256(gbase, lbase) { \
    _Pragma("unroll") \
    for (int j_=0; j_<4; ++j_) \
      __builtin_amdgcn_global_load_lds((gptr_t)((gbase) + j_*4096 + (wave<<10) + (lane<<4)), \
                                       (lptr_t)((lbase) + j_*4096 + (wave<<10)), 16, 0, 0); \
  }

// ---------------- prep: pack conv weights to [tap][kg][cout][8] fp16 ----------------
__global__ void pack_w(const float* __restrict__ w1, const float* __restrict__ w2,
                       u16* __restrict__ Wp1, u16* __restrict__ Wp2){
  int i = blockIdx.x * 256 + threadIdx.x;
  const int N1 = KW * 12 * FILT;          // 27648
  const int N2 = KW * 32 * FILT;          // 73728
  if (i < N1){
    int tap = i / (12*FILT); int r = i - tap*12*FILT; int kg = r / FILT; int co = r - kg*FILT;
    short8 v;
    #pragma unroll
    for (int e=0;e<8;e++){
      int ci = kg*8 + e;
      float x = (ci < NMEL) ? w1[(co*NMEL + ci)*KW + tap] : 0.f;
      v[e] = (short)f2h(x);
    }
    *(short8*)(Wp1 + (size_t)i*8) = v;
  } else if (i < N1 + N2){
    int j = i - N1;
    int tap = j / (32*FILT); int r = j - tap*32*FILT; int kg = r / FILT; int co = r - kg*FILT;
    short8 v;
    #pragma unroll
    for (int e=0;e<8;e++){
      int ci = kg*8 + e;
      v[e] = (short)f2h(w2[(co*FILT + ci)*KW + tap]);
    }
    *(short8*)(Wp2 + (size_t)j*8) = v;
  }
}

// ---------------- prep: mels -> padded fp16 [B][T+8][104], vectorized ----------------
__global__ void prep_mels(const float* __restrict__ mels, u16* __restrict__ melsPad){
  int idx = blockIdx.x * 256 + threadIdx.x;
  if (idx >= B_*TP8*13) return;
  int ch = idx % 13; int r = idx / 13; int row = r % TP8; int b = r / TP8;
  int t = row - 4;
  short8 v = (short8){0,0,0,0,0,0,0,0};
  if (t >= 0 && t < T_ && ch < 10){
    const float* src = mels + ((size_t)b*T_ + t)*NMEL + ch*8;
    const f32x4 f0 = *(const f32x4*)src;
    const f32x4 f1 = *(const f32x4*)(src+4);
    #pragma unroll
    for (int j=0;j<4;j++){ v[j]=(short)f2h(f0[j]); v[4+j]=(short)f2h(f1[j]); }
  }
  *(short8*)(melsPad + (size_t)idx*8) = v;
}

// ---------------- prep: cumsums (LDS scan), frame->phone, phone->word, zero y1 halos ----------------
__global__ void prep_seg(const int* __restrict__ dur, const int* __restrict__ wpl,
                         int* __restrict__ wcum,
                         int* __restrict__ pid, int* __restrict__ wid,
                         u16* __restrict__ y1Pad){
  int b = blockIdx.x; int tid = threadIdx.x;
  __shared__ int dc[P_];
  __shared__ int wc[W_];
  for (int p=tid; p<P_; p+=256) dc[p] = dur[b*P_+p];
  if (tid < W_) wc[tid] = wpl[b*W_+tid];
  __syncthreads();
  if (tid == 0){ int run=0; for (int p=0;p<P_;p++){ run += dc[p]; dc[p]=run; } }
  if (tid == 64){ int run=0; for (int w=0;w<W_;w++){ run += wc[w]; wc[w]=run; wcum[b*W_+w]=run; } }
  __syncthreads();
  for (int t=tid; t<T_; t+=256){
    int lo=0, hi=P_;
    while (lo < hi){ int mid=(lo+hi)>>1; if (dc[mid] > t) hi=mid; else lo=mid+1; }
    pid[b*T_+t] = lo;
  }
  for (int p=tid; p<P_; p+=256){
    int lo=0, hi=W_;
    while (lo < hi){ int mid=(lo+hi)>>1; if (wc[mid] > p) hi=mid; else lo=mid+1; }
    wid[b*P_+p] = min(lo, W_-1);
  }
  for (int i=tid; i<8*YSTR; i+=256){
    int rr = i / YSTR; int cc = i - rr*YSTR;
    int row = (rr < 4) ? rr : (T_ + rr);
    y1Pad[((size_t)b*TP8 + row)*YSTR + cc] = 0;
  }
}

// ---------------- conv1 + bias + relu + LN1 -> y1Pad fp16 (32x32x16, 64-row tile) ----------------
// 256 thr / 4 waves, wave tile 64x64 (acc 2x2 f32x16). 27 x 16KB chunks,
// ring-2, stage-ahead-1, counted vmcnt, 1 s_barrier/iter.
// LDS 14,976(A) + 32,768(ring) ~ 48 KB -> 3 blocks/CU.
__global__ __launch_bounds__(256, 3) void conv1_k(
    const u16* __restrict__ melsPad, const u16* __restrict__ Wp1,
    const float* __restrict__ bias, const float* __restrict__ lng,
    const float* __restrict__ lnb, u16* __restrict__ y1Pad){
  __shared__ __align__(16) u16 sA[7488];        // 14,976 B: 72 rows x 104
  __shared__ __align__(16) u16 sR[2*8192];      // 2 x 16,384 B ring
  const int tid = threadIdx.x;
  const int wave = tid >> 6, lane = tid & 63, l31 = lane & 31, h = lane >> 5;
  const int b = blockIdx.y, t0 = blockIdx.x * 64;

  float bcol[2], gcol[2], btcol[2];
  #pragma unroll
  for (int n=0;n<2;n++){
    int c = wave*64 + n*32 + l31;
    bcol[n]=bias[c]; gcol[n]=lng[c]; btcol[n]=lnb[c];
  }

  {
    const char* gA = (const char*)(melsPad + ((size_t)b*TP8 + t0)*MSTR);
    #pragma unroll
    for (int it=0; it<4; ++it)
      if (it*4096 + tid*16 < 14976)
        __builtin_amdgcn_global_load_lds((gptr_t)(gA + it*4096 + (wave<<10) + (lane<<4)),
                                         (lptr_t)((char*)sA + it*4096 + (wave<<10)), 16, 0, 0);
  }
  const char* gW = (const char*)Wp1;
  char* ring = (char*)sR;
  STAGE16K_256(gW, ring)
  __syncthreads();   // full drain: vmcnt = 0 at loop entry

  f32x16 acc00={}, acc01={}, acc10={}, acc11={};
  const int coB = wave*64 + l31;

#define C1_IT(cc, WN) { \
    __builtin_amdgcn_s_barrier(); \
    __builtin_amdgcn_sched_barrier(0); \
    if ((cc)+1 < 27) STAGE16K_256(gW + (size_t)((cc)+1)*16384, ring + ((((cc)+1)&1)<<14)) \
    asm volatile("s_waitcnt vmcnt(" #WN ")" ::: "memory"); \
    __builtin_amdgcn_sched_barrier(0); \
    const int tap_=(cc)/3, s_=(cc)%3; \
    const u16* bufB = (const u16*)(ring + (((cc)&1)<<14)); \
    const u16* pA = sA + (l31 + tap_)*MSTR + s_*32 + h*8; \
    short8 a0 = *(const short8*)(pA); \
    short8 a1 = *(const short8*)(pA + 16); \
    short8 a2 = *(const short8*)(pA + 32*MSTR); \
    short8 a3 = *(const short8*)(pA + 32*MSTR + 16); \
    const u16* pB = bufB + ((size_t)h*256 + coB)*8; \
    short8 b0 = *(const short8*)(pB); \
    short8 b1 = *(const short8*)(pB + 2*256*8); \
    short8 b2 = *(const short8*)(pB + 32*8); \
    short8 b3 = *(const short8*)(pB + 2*256*8 + 32*8); \
    asm volatile("s_waitcnt lgkmcnt(0)" ::: "memory"); \
    __builtin_amdgcn_sched_barrier(0); \
    __builtin_amdgcn_s_setprio(1); \
    MFMA32(acc00, a0, b0); MFMA32(acc00, a1, b1); \
    MFMA32(acc10, a2, b0); MFMA32(acc10, a3, b1); \
    MFMA32(acc01, a0, b2); MFMA32(acc01, a1, b3); \
    MFMA32(acc11, a2, b2); MFMA32(acc11, a3, b3); \
    __builtin_amdgcn_s_setprio(0); \
  }

  #pragma unroll 1
  for (int cc=0; cc<26; ++cc) C1_IT(cc, 4)
  C1_IT(26, 0)

  asm volatile("s_nop 7\n\ts_nop 7\n\ts_nop 7" :: );
  __syncthreads();

  float* sred  = (float*)sR;     // [64][4]
  float* sred2 = sred + 256;
  float* smean = sred2 + 256;    // [64]
  float* srstd = smean + 64;

#define LNSUM64(mb, A0, A1) \
  _Pragma("unroll") for (int r=0;r<16;++r){ \
    float v0 = fmaxf(A0[r] + bcol[0], 0.f); \
    float v1 = fmaxf(A1[r] + bcol[1], 0.f); \
    float s = v0+v1, qq = v0*v0+v1*v1; \
    _Pragma("unroll") for (int off=1; off<32; off<<=1){ s += __shfl_xor(s, off); qq += __shfl_xor(qq, off); } \
    if (l31 == 0){ int row = (mb)*32 + (r&3) + 8*(r>>2) + 4*h; \
      sred[row*4+wave]=s; sred2[row*4+wave]=qq; } \
  }
  LNSUM64(0, acc00, acc01)
  LNSUM64(1, acc10, acc11)
  __syncthreads();
  if (tid < 64){
    float ss=0.f, qq=0.f;
    #pragma unroll
    for (int w2=0; w2<4; w2++){ ss += sred[tid*4+w2]; qq += sred2[tid*4+w2]; }
    float mean = ss * (1.f/FILT);
    float var  = qq * (1.f/FILT) - mean*mean;
    smean[tid] = mean;
    srstd[tid] = rsqrtf(fmaxf(var, 0.f) + EPS);
  }
  __syncthreads();

#define EMIT1(mb, A0, A1) \
  _Pragma("unroll") for (int q=0;q<4;++q){ \
    const int rbase = (mb)*32 + q*8 + 4*h; \
    float mn0=smean[rbase+0],mn1=smean[rbase+1],mn2=smean[rbase+2],mn3=smean[rbase+3]; \
    float rs0=srstd[rbase+0],rs1=srstd[rbase+1],rs2=srstd[rbase+2],rs3=srstd[rbase+3]; \
    _Pragma("unroll") for (int nb=0;nb<2;++nb){ \
      int c = wave*64 + nb*32 + l31; \
      float x0 = fmaxf((nb? A1[q*4+0] : A0[q*4+0]) + bcol[nb], 0.f); \
      float x1 = fmaxf((nb? A1[q*4+1] : A0[q*4+1]) + bcol[nb], 0.f); \
      float x2 = fmaxf((nb? A1[q*4+2] : A0[q*4+2]) + bcol[nb], 0.f); \
      float x3 = fmaxf((nb? A1[q*4+3] : A0[q*4+3]) + bcol[nb], 0.f); \
      u16* dst = y1Pad + ((size_t)b*TP8 + 4 + t0 + rbase)*YSTR + c; \
      dst[0*YSTR] = f2h((x0-mn0)*rs0*gcol[nb]+btcol[nb]); \
      dst[1*YSTR] = f2h((x1-mn1)*rs1*gcol[nb]+btcol[nb]); \
      dst[2*YSTR] = f2h((x2-mn2)*rs2*gcol[nb]+btcol[nb]); \
      dst[3*YSTR] = f2h((x3-mn3)*rs3*gcol[nb]+btcol[nb]); \
    } \
  }
  EMIT1(0, acc00, acc01)
  EMIT1(1, acc10, acc11)
}

// ---------------- conv2 + bias + relu + LN2 -> phone-sum atomics (32x32x16, 64-row) ----------------
// 256 thr / 4 waves, wave tile 64x64. 72 x 16KB chunks, ring-2, stage-ahead-1.
// LDS 38,016(A) + 32,768(ring) ~ 71 KB -> 2 blocks/CU.
__global__ __launch_bounds__(256, 2) void conv2_k(
    const u16* __restrict__ y1Pad, const u16* __restrict__ Wp2,
    const float* __restrict__ bias, const float* __restrict__ lng,
    const float* __restrict__ lnb, const int* __restrict__ pid,
    float* __restrict__ ps){
  __shared__ __align__(16) u16 sA[19008];       // 38,016 B: 72 rows x 264
  __shared__ __align__(16) u16 sR[2*8192];      // 2 x 16,384 B ring
  __shared__ int pidT[64];
  const int tid = threadIdx.x;
  const int wave = tid >> 6, lane = tid & 63, l31 = lane & 31, h = lane >> 5;
  const int b = blockIdx.y, t0 = blockIdx.x * 64;

  float bcol[2], gcol[2], btcol[2];
  #pragma unroll
  for (int n=0;n<2;n++){
    int c = wave*64 + n*32 + l31;
    bcol[n]=bias[c]; gcol[n]=lng[c]; btcol[n]=lnb[c];
  }
  if (tid < 64) pidT[tid] = pid[b*T_ + t0 + tid];

  {
    const char* gA = (const char*)(y1Pad + ((size_t)b*TP8 + t0)*YSTR);
    #pragma unroll
    for (int it=0; it<10; ++it)
      if (it*4096 + tid*16 < 38016)
        __builtin_amdgcn_global_load_lds((gptr_t)(gA + it*4096 + (wave<<10) + (lane<<4)),
                                         (lptr_t)((char*)sA + it*4096 + (wave<<10)), 16, 0, 0);
  }
  const char* gW = (const char*)Wp2;
  char* ring = (char*)sR;
  STAGE16K_256(gW, ring)
  __syncthreads();   // full drain: vmcnt = 0 at loop entry

  f32x16 acc00={}, acc01={}, acc10={}, acc11={};
  const int coB = wave*64 + l31;

#define C2_IT(cc, WN) { \
    __builtin_amdgcn_s_barrier(); \
    __builtin_amdgcn_sched_barrier(0); \
    if ((cc)+1 < 72) STAGE16K_256(gW + (size_t)((cc)+1)*16384, ring + ((((cc)+1)&1)<<14)) \
    asm volatile("s_waitcnt vmcnt(" #WN ")" ::: "memory"); \
    __builtin_amdgcn_sched_barrier(0); \
    const int tap_=(cc)>>3, sg_=(cc)&7; \
    const u16* bufB = (const u16*)(ring + (((cc)&1)<<14)); \
    const u16* pA = sA + (l31 + tap_)*YSTR + sg_*32 + h*8; \
    short8 a0 = *(const short8*)(pA); \
    short8 a1 = *(const short8*)(pA + 16); \
    short8 a2 = *(const short8*)(pA + 32*YSTR); \
    short8 a3 = *(const short8*)(pA + 32*YSTR + 16); \
    const u16* pB = bufB + ((size_t)h*256 + coB)*8; \
    short8 b0 = *(const short8*)(pB); \
    short8 b1 = *(const short8*)(pB + 2*256*8); \
    short8 b2 = *(const short8*)(pB + 32*8); \
    short8 b3 = *(const short8*)(pB + 2*256*8 + 32*8); \
    asm volatile("s_waitcnt lgkmcnt(0)" ::: "memory"); \
    __builtin_amdgcn_sched_barrier(0); \
    __builtin_amdgcn_s_setprio(1); \
    MFMA32(acc00, a0, b0); MFMA32(acc00, a1, b1); \
    MFMA32(acc10, a2, b0); MFMA32(acc10, a3, b1); \
    MFMA32(acc01, a0, b2); MFMA32(acc01, a1, b3); \
    MFMA32(acc11, a2, b2); MFMA32(acc11, a3, b3); \
    __builtin_amdgcn_s_setprio(0); \
  }

  #pragma unroll 1
  for (int cc=0; cc<71; ++cc) C2_IT(cc, 4)
  C2_IT(71, 0)

  asm volatile("s_nop 7\n\ts_nop 7\n\ts_nop 7" :: );
  __syncthreads();

  float* sred  = (float*)sR;     // [64][4]
  float* sred2 = sred + 256;
  float* smean = sred2 + 256;    // [64]
  float* srstd = smean + 64;

  LNSUM64(0, acc00, acc01)
  LNSUM64(1, acc10, acc11)
  __syncthreads();
  if (tid < 64){
    float ss=0.f, qq=0.f;
    #pragma unroll
    for (int w2=0; w2<4; w2++){ ss += sred[tid*4+w2]; qq += sred2[tid*4+w2]; }
    float mean = ss * (1.f/FILT);
    float var  = qq * (1.f/FILT) - mean*mean;
    smean[tid] = mean;
    srstd[tid] = rsqrtf(fmaxf(var, 0.f) + EPS);
  }
  __syncthreads();

#define EMIT2(mb, A0, A1) \
  _Pragma("unroll") for (int q=0;q<4;++q){ \
    const int rbase = (mb)*32 + q*8 + 4*h; \
    int p0v = pidT[rbase]; int fold = (p0v == pidT[rbase+3]); \
    float mn0=smean[rbase+0],mn1=smean[rbase+1],mn2=smean[rbase+2],mn3=smean[rbase+3]; \
    float rs0=srstd[rbase+0],rs1=srstd[rbase+1],rs2=srstd[rbase+2],rs3=srstd[rbase+3]; \
    int pp = __shfl_xor(p0v, 32); int fp = __shfl_xor(fold, 32); \
    _Pragma("unroll") for (int nb=0;nb<2;++nb){ \
      int c = wave*64 + nb*32 + l31; \
      float x0 = fmaxf((nb? A1[q*4+0] : A0[q*4+0]) + bcol[nb], 0.f); \
      float x1 = fmaxf((nb? A1[q*4+1] : A0[q*4+1]) + bcol[nb], 0.f); \
      float x2 = fmaxf((nb? A1[q*4+2] : A0[q*4+2]) + bcol[nb], 0.f); \
      float x3 = fmaxf((nb? A1[q*4+3] : A0[q*4+3]) + bcol[nb], 0.f); \
      float o0 = (x0-mn0)*rs0*gcol[nb]+btcol[nb]; \
      float o1 = (x1-mn1)*rs1*gcol[nb]+btcol[nb]; \
      float o2 = (x2-mn2)*rs2*gcol[nb]+btcol[nb]; \
      float o3 = (x3-mn3)*rs3*gcol[nb]+btcol[nb]; \
      float s4 = fold ? (o0+o1+o2+o3) : 0.f; \
      float sp = __shfl_xor(s4, 32); \
      float* basep = ps + (size_t)b*P_*FILT; \
      if (fold){ \
        if (p0v < P_){ \
          if (fp && pp == p0v){ if (h == 0) atomicAdd(basep + (size_t)p0v*FILT + c, s4 + sp); } \
          else atomicAdd(basep + (size_t)p0v*FILT + c, s4); \
        } \
      } else { \
        int pj; \
        pj = pidT[rbase+0]; if (pj < P_) atomicAdd(basep + (size_t)pj*FILT + c, o0); \
        pj = pidT[rbase+1]; if (pj < P_) atomicAdd(basep + (size_t)pj*FILT + c, o1); \
        pj = pidT[rbase+2]; if (pj < P_) atomicAdd(basep + (size_t)pj*FILT + c, o2); \
        pj = pidT[rbase+3]; if (pj < P_) atomicAdd(basep + (size_t)pj*FILT + c, o3); \
      } \
    } \
  }
  EMIT2(0, acc00, acc01)
  EMIT2(1, acc10, acc11)
}

// ---------------- word pooling + MLP: 8 words per block ----------------
#define WPB 8
__global__ __launch_bounds__(256) void word_k(
    const float* __restrict__ ps, const int* __restrict__ dur,
    const int* __restrict__ wcum, const int* __restrict__ wpl,
    const float* __restrict__ w1, const float* __restrict__ b1,
    const float* __restrict__ w2, const float* __restrict__ b2,
    float* __restrict__ wemb){
  int b = blockIdx.y, wg = blockIdx.x * WPB, tid = threadIdx.x;
  __shared__ float wvS[WPB][FILT];
  __shared__ float h1S[WPB][FILT];
  #pragma unroll
  for (int k=0;k<WPB;k++){
    int w = wg + k;
    int p1 = wcum[b*W_ + w]; int p0 = (w == 0) ? 0 : wcum[b*W_ + w - 1];
    if (p1 > P_) p1 = P_;
    int len = wpl[b*W_ + w];
    float a = 0.f;
    for (int p = p0; p < p1; ++p){
      int d = dur[b*P_ + p]; d = d < 1 ? 1 : d;
      a += ps[((size_t)(b*P_ + p))*FILT + tid] / (float)d;
    }
    wvS[k][tid] = a / (float)(len < 1 ? 1 : len);
  }
  __syncthreads();
  float acc[WPB];
  #pragma unroll
  for (int k=0;k<WPB;k++) acc[k] = b1[tid];
  for (int i=0;i<FILT;i++){
    float wcol = w1[i*FILT + tid];
    #pragma unroll
    for (int k=0;k<WPB;k++) acc[k] += wvS[k][i] * wcol;
  }
  #pragma unroll
  for (int k=0;k<WPB;k++) h1S[k][tid] = fmaxf(acc[k], 0.f);
  __syncthreads();
  int c = tid & 63, kq = tid >> 6;
  #pragma unroll
  for (int kk=kq; kk<WPB; kk+=4){
    float u = b2[c];
    for (int i=0;i<FILT;i++) u += h1S[kk][i] * w2[i*PDIM + c];
    wemb[((size_t)(b*W_ + wg + kk))*PDIM + c] = fmaxf(u, 0.f);
  }
}

// ---------------- expand words -> phones + mask (float4) ----------------
__global__ void expand_k(const float* __restrict__ wemb, const int* __restrict__ wid,
                         const unsigned char* __restrict__ mask, float* __restrict__ out){
  int idx = blockIdx.x * 256 + threadIdx.x;
  if (idx >= B_*P_*16) return;
  int q = idx & 15; int p = (idx >> 4) & 511; int bb = idx >> 13;
  int w = wid[bb*P_ + p];
  f32x4 v = *(const f32x4*)(wemb + ((size_t)(bb*W_ + w))*PDIM + q*4);
  if (mask[bb*P_ + p]) v = (f32x4){0.f,0.f,0.f,0.f};
  *(f32x4*)(out + (size_t)idx*4) = v;
}

extern "C" void kernel_launch(void* const* d_in, const int* in_sizes, int n_in,
                              void* d_out, int out_size, void* d_ws, size_t ws_size,
                              hipStream_t stream) {
  const unsigned char* mask = (const unsigned char*)d_in[0];
  const float* mels = (const float*)d_in[1];
  const int*   dur  = (const int*)d_in[3];
  const int*   wpl  = (const int*)d_in[4];
  const float* c1w  = (const float*)d_in[5];
  const float* c1b  = (const float*)d_in[6];
  const float* l1g  = (const float*)d_in[7];
  const float* l1b  = (const float*)d_in[8];
  const float* c2w  = (const float*)d_in[9];
  const float* c2b  = (const float*)d_in[10];
  const float* l2g  = (const float*)d_in[11];
  const float* l2b  = (const float*)d_in[12];
  const float* w1   = (const float*)d_in[13];
  const float* b1   = (const float*)d_in[14];
  const float* w2   = (const float*)d_in[15];
  const float* b2   = (const float*)d_in[16];

  char* ws = (char*)d_ws;
  size_t off = 0;
  auto alloc = [&](size_t bytes){ void* p = ws + off; off += (bytes + 255) & ~(size_t)255; return p; };
  u16* melsPad = (u16*)alloc((size_t)B_*TP8*MSTR*2 + 32768);
  u16* y1Pad   = (u16*)alloc((size_t)B_*TP8*YSTR*2 + 32768);
  u16* Wp1     = (u16*)alloc((size_t)KW*12*FILT*8*2);
  u16* Wp2     = (u16*)alloc((size_t)KW*32*FILT*8*2 + 32768);
  int* wcum    = (int*)alloc((size_t)B_*W_*4);
  int* pid     = (int*)alloc((size_t)B_*T_*4);
  int* wid     = (int*)alloc((size_t)B_*P_*4);
  float* psum  = (float*)alloc((size_t)B_*P_*FILT*4);
  float* wemb  = (float*)alloc((size_t)B_*W_*PDIM*4);

  hipMemsetAsync(psum, 0, (size_t)B_*P_*FILT*4, stream);
  pack_w<<<(KW*12*FILT + KW*32*FILT + 255)/256, 256, 0, stream>>>(c1w, c2w, Wp1, Wp2);
  prep_mels<<<(B_*TP8*13 + 255)/256, 256, 0, stream>>>(mels, melsPad);
  prep_seg<<<B_, 256, 0, stream>>>(dur, wpl, wcum, pid, wid, y1Pad);
  conv1_k<<<dim3(T_/64, B_), 256, 0, stream>>>(melsPad, Wp1, c1b, l1g, l1b, y1Pad);
  conv2_k<<<dim3(T_/64, B_), 256, 0, stream>>>(y1Pad, Wp2, c2b, l2g, l2b, pid, psum);
  word_k<<<dim3(W_/WPB, B_), 256, 0, stream>>>(psum, dur, wcum, wpl, w1, b1, w2, b2, wemb);
  expand_k<<<(B_*P_*16 + 255)/256, 256, 0, stream>>>(wemb, wid, mask, (float*)d_out);
}

// Round 8
// 351.873 us; speedup vs baseline: 1.2053x; 1.2053x over previous
//
#include <hip/hip_runtime.h>
#include <hip/hip_fp16.h>
#include <stdint.h>

#define B_ 32
#define T_ 4096
#define P_ 512
#define W_ 128
#define NMEL 80
#define FILT 256
#define PDIM 64
#define KW 9
#define TP8 (T_ + 8)
#define MSTR 104
#define YSTR 264
#define EPS 1e-5f

typedef unsigned short u16;
typedef __attribute__((ext_vector_type(8))) short short8;
typedef __attribute__((ext_vector_type(4))) float f32x4;
typedef __attribute__((ext_vector_type(16))) float f32x16;

typedef const __attribute__((address_space(1))) uint32_t* gptr_t;
typedef __attribute__((address_space(3))) uint32_t* lptr_t;

__device__ __forceinline__ u16 f2h(float v){ return __half_as_ushort(__float2half(v)); }

#define MFMA32(accv, av, bv) \
  asm volatile("v_mfma_f32_32x32x16_f16 %0, %1, %2, %0" : "+v"(accv) : "v"(av), "v"(bv))

// ---------------- prep: pack conv weights to [kg][cout][8] fp16 ----------------
__global__ void pack_w(const float* __restrict__ w1, const float* __restrict__ w2,
                       u16* __restrict__ Wp1, u16* __restrict__ Wp2){
  int i = blockIdx.x * 256 + threadIdx.x;
  const int N1 = KW * 12 * FILT;          // 27648
  const int N2 = KW * 32 * FILT;          // 73728
  if (i < N1){
    int tap = i / (12*FILT); int r = i - tap*12*FILT; int kg = r / FILT; int co = r - kg*FILT;
    short8 v;
    #pragma unroll
    for (int e=0;e<8;e++){
      int ci = kg*8 + e;
      float x = (ci < NMEL) ? w1[(co*NMEL + ci)*KW + tap] : 0.f;
      v[e] = (short)f2h(x);
    }
    *(short8*)(Wp1 + (size_t)i*8) = v;
  } else if (i < N1 + N2){
    int j = i - N1;
    int tap = j / (32*FILT); int r = j - tap*32*FILT; int kg = r / FILT; int co = r - kg*FILT;
    short8 v;
    #pragma unroll
    for (int e=0;e<8;e++){
      int ci = kg*8 + e;
      v[e] = (short)f2h(w2[(co*FILT + ci)*KW + tap]);
    }
    *(short8*)(Wp2 + (size_t)j*8) = v;
  }
}

// ---------------- prep: mels -> padded fp16 [B][T+8][104], vectorized ----------------
__global__ void prep_mels(const float* __restrict__ mels, u16* __restrict__ melsPad){
  int idx = blockIdx.x * 256 + threadIdx.x;
  if (idx >= B_*TP8*13) return;
  int ch = idx % 13; int r = idx / 13; int row = r % TP8; int b = r / TP8;
  int t = row - 4;
  short8 v = (short8){0,0,0,0,0,0,0,0};
  if (t >= 0 && t < T_ && ch < 10){
    const float* src = mels + ((size_t)b*T_ + t)*NMEL + ch*8;
    const f32x4 f0 = *(const f32x4*)src;
    const f32x4 f1 = *(const f32x4*)(src+4);
    #pragma unroll
    for (int j=0;j<4;j++){ v[j]=(short)f2h(f0[j]); v[4+j]=(short)f2h(f1[j]); }
  }
  *(short8*)(melsPad + (size_t)idx*8) = v;
}

// ---------------- prep: cumsums (LDS scan), frame->phone, phone->word, zero y1 halos ----------------
__global__ void prep_seg(const int* __restrict__ dur, const int* __restrict__ wpl,
                         int* __restrict__ wcum,
                         int* __restrict__ pid, int* __restrict__ wid,
                         u16* __restrict__ y1Pad){
  int b = blockIdx.x; int tid = threadIdx.x;
  __shared__ int dc[P_];
  __shared__ int wc[W_];
  for (int p=tid; p<P_; p+=256) dc[p] = dur[b*P_+p];
  if (tid < W_) wc[tid] = wpl[b*W_+tid];
  __syncthreads();
  if (tid == 0){ int run=0; for (int p=0;p<P_;p++){ run += dc[p]; dc[p]=run; } }
  if (tid == 64){ int run=0; for (int w=0;w<W_;w++){ run += wc[w]; wc[w]=run; wcum[b*W_+w]=run; } }
  __syncthreads();
  for (int t=tid; t<T_; t+=256){
    int lo=0, hi=P_;
    while (lo < hi){ int mid=(lo+hi)>>1; if (dc[mid] > t) hi=mid; else lo=mid+1; }
    pid[b*T_+t] = lo;
  }
  for (int p=tid; p<P_; p+=256){
    int lo=0, hi=W_;
    while (lo < hi){ int mid=(lo+hi)>>1; if (wc[mid] > p) hi=mid; else lo=mid+1; }
    wid[b*P_+p] = min(lo, W_-1);
  }
  for (int i=tid; i<8*YSTR; i+=256){
    int rr = i / YSTR; int cc = i - rr*YSTR;
    int row = (rr < 4) ? rr : (T_ + rr);
    y1Pad[((size_t)b*TP8 + row)*YSTR + cc] = 0;
  }
}

// ---------------- conv1 + bias + relu + LN1 -> y1Pad fp16 ----------------
// M=128 rows/block, 256 thr / 4 waves (wave = 64-cout group). A (28 KB) in LDS
// staged once; B fragments DIRECT global->reg (coalesced dwordx4, L2-resident),
// 1-iter register rotate. NO barriers / waitcnt asm in K-loop.
__global__ __launch_bounds__(256, 2) void conv1_k(
    const u16* __restrict__ melsPad, const u16* __restrict__ Wp1,
    const float* __restrict__ bias, const float* __restrict__ lng,
    const float* __restrict__ lnb, u16* __restrict__ y1Pad){
  __shared__ __align__(16) u16 sA[14144];   // 28,288 B: 136 rows x 104
  __shared__ float sred[512], sred2[512], smean[128], srstd[128];
  const int tid = threadIdx.x;
  const int cg = tid >> 6, lane = tid & 63, l31 = lane & 31, h = lane >> 5;
  const int b = blockIdx.y, t0 = blockIdx.x * 128;

  float bcol[2], gcol[2], btcol[2];
  #pragma unroll
  for (int n=0;n<2;n++){
    int c = cg*64 + n*32 + l31;
    bcol[n]=bias[c]; gcol[n]=lng[c]; btcol[n]=lnb[c];
  }

  {
    const char* gA = (const char*)(melsPad + ((size_t)b*TP8 + t0)*MSTR);
    #pragma unroll
    for (int it=0; it<7; ++it)
      if (it*4096 + tid*16 < 28288)
        __builtin_amdgcn_global_load_lds((gptr_t)(gA + it*4096 + (cg<<10) + (lane<<4)),
                                         (lptr_t)((char*)sA + it*4096 + (cg<<10)), 16, 0, 0);
  }

  const char* gB = (const char*)Wp1 + h*4096 + cg*1024 + (l31<<4);
#define LOADB1(cc, D) { const char* nb_ = gB + (size_t)(cc)*16384; \
    D[0][0]=*(const short8*)(nb_);      D[0][1]=*(const short8*)(nb_+512); \
    D[1][0]=*(const short8*)(nb_+8192); D[1][1]=*(const short8*)(nb_+8704); }

  short8 nb[2][2];
  LOADB1(0, nb)
  __syncthreads();   // A resident; vmcnt drained

  f32x16 acc[2][2][2] = {};

  #pragma unroll 2
  for (int cc=0; cc<27; ++cc){
    short8 bb[2][2];
    #pragma unroll
    for (int s2=0;s2<2;++s2)
      #pragma unroll
      for (int cb=0;cb<2;++cb) bb[s2][cb] = nb[s2][cb];
    if (cc+1 < 27) LOADB1(cc+1, nb)
    const int tap = cc/3, s = cc - tap*3;
    const u16* pA = sA + (l31 + tap)*MSTR + s*32 + h*8;
    #pragma unroll
    for (int st=0; st<2; ++st){
      short8 a[2][2];
      #pragma unroll
      for (int rb=0; rb<2; ++rb)
        #pragma unroll
        for (int s2=0; s2<2; ++s2)
          a[rb][s2] = *(const short8*)(pA + (st*64 + rb*32)*MSTR + s2*16);
      #pragma unroll
      for (int rb=0; rb<2; ++rb){
        MFMA32(acc[st][rb][0], a[rb][0], bb[0][0]);
        MFMA32(acc[st][rb][0], a[rb][1], bb[1][0]);
        MFMA32(acc[st][rb][1], a[rb][0], bb[0][1]);
        MFMA32(acc[st][rb][1], a[rb][1], bb[1][1]);
      }
    }
  }

  asm volatile("s_nop 7\n\ts_nop 7\n\ts_nop 7" :: );

  #pragma unroll
  for (int st=0;st<2;++st)
    #pragma unroll
    for (int rb=0;rb<2;++rb)
      #pragma unroll
      for (int r=0;r<16;++r){
        float v0 = fmaxf(acc[st][rb][0][r] + bcol[0], 0.f);
        float v1 = fmaxf(acc[st][rb][1][r] + bcol[1], 0.f);
        float s = v0+v1, q = v0*v0+v1*v1;
        #pragma unroll
        for (int off=1; off<32; off<<=1){ s += __shfl_xor(s, off); q += __shfl_xor(q, off); }
        if (l31 == 0){ int row = st*64 + rb*32 + (r&3) + 8*(r>>2) + 4*h;
          sred[row*4+cg]=s; sred2[row*4+cg]=q; }
      }
  __syncthreads();
  if (tid < 128){
    float ss=0.f, qq=0.f;
    #pragma unroll
    for (int w2=0; w2<4; w2++){ ss += sred[tid*4+w2]; qq += sred2[tid*4+w2]; }
    float mean = ss * (1.f/FILT);
    float var  = qq * (1.f/FILT) - mean*mean;
    smean[tid] = mean;
    srstd[tid] = rsqrtf(fmaxf(var, 0.f) + EPS);
  }
  __syncthreads();

  #pragma unroll
  for (int st=0;st<2;++st)
    #pragma unroll
    for (int rb=0;rb<2;++rb)
      #pragma unroll
      for (int q=0;q<4;++q){
        const int rbase = st*64 + rb*32 + q*8 + 4*h;
        float mn0=smean[rbase+0],mn1=smean[rbase+1],mn2=smean[rbase+2],mn3=smean[rbase+3];
        float rs0=srstd[rbase+0],rs1=srstd[rbase+1],rs2=srstd[rbase+2],rs3=srstd[rbase+3];
        #pragma unroll
        for (int cb=0;cb<2;++cb){
          int c = cg*64 + cb*32 + l31;
          float x0 = fmaxf(acc[st][rb][cb][q*4+0] + bcol[cb], 0.f);
          float x1 = fmaxf(acc[st][rb][cb][q*4+1] + bcol[cb], 0.f);
          float x2 = fmaxf(acc[st][rb][cb][q*4+2] + bcol[cb], 0.f);
          float x3 = fmaxf(acc[st][rb][cb][q*4+3] + bcol[cb], 0.f);
          u16* dst = y1Pad + ((size_t)b*TP8 + 4 + t0 + rbase)*YSTR + c;
          dst[0*YSTR] = f2h((x0-mn0)*rs0*gcol[cb]+btcol[cb]);
          dst[1*YSTR] = f2h((x1-mn1)*rs1*gcol[cb]+btcol[cb]);
          dst[2*YSTR] = f2h((x2-mn2)*rs2*gcol[cb]+btcol[cb]);
          dst[3*YSTR] = f2h((x3-mn3)*rs3*gcol[cb]+btcol[cb]);
        }
      }
}

// ---------------- conv2 + bias + relu + LN2 -> phone-sum atomics ----------------
// M=128 rows/block, 256 thr / 4 waves. A (71.8 KB) in LDS once; B direct
// global->reg with rotate; barrier-free K-loop (72 iters).
__global__ __launch_bounds__(256, 2) void conv2_k(
    const u16* __restrict__ y1Pad, const u16* __restrict__ Wp2,
    const float* __restrict__ bias, const float* __restrict__ lng,
    const float* __restrict__ lnb, const int* __restrict__ pid,
    float* __restrict__ ps){
  __shared__ __align__(16) u16 sA[35904];   // 71,808 B: 136 rows x 264
  __shared__ float sred[512], sred2[512], smean[128], srstd[128];
  __shared__ int pidT[128];
  const int tid = threadIdx.x;
  const int cg = tid >> 6, lane = tid & 63, l31 = lane & 31, h = lane >> 5;
  const int b = blockIdx.y, t0 = blockIdx.x * 128;

  float bcol[2], gcol[2], btcol[2];
  #pragma unroll
  for (int n=0;n<2;n++){
    int c = cg*64 + n*32 + l31;
    bcol[n]=bias[c]; gcol[n]=lng[c]; btcol[n]=lnb[c];
  }
  if (tid < 128) pidT[tid] = pid[b*T_ + t0 + tid];

  {
    const char* gA = (const char*)(y1Pad + ((size_t)b*TP8 + t0)*YSTR);
    #pragma unroll
    for (int it=0; it<18; ++it)
      if (it*4096 + tid*16 < 71808)
        __builtin_amdgcn_global_load_lds((gptr_t)(gA + it*4096 + (cg<<10) + (lane<<4)),
                                         (lptr_t)((char*)sA + it*4096 + (cg<<10)), 16, 0, 0);
  }

  const char* gB = (const char*)Wp2 + h*4096 + cg*1024 + (l31<<4);
#define LOADB2(cc, D) { const char* nb_ = gB + (size_t)(cc)*16384; \
    D[0][0]=*(const short8*)(nb_);      D[0][1]=*(const short8*)(nb_+512); \
    D[1][0]=*(const short8*)(nb_+8192); D[1][1]=*(const short8*)(nb_+8704); }

  short8 nb[2][2];
  LOADB2(0, nb)
  __syncthreads();   // A resident; vmcnt drained

  f32x16 acc[2][2][2] = {};

  #pragma unroll 2
  for (int cc=0; cc<72; ++cc){
    short8 bb[2][2];
    #pragma unroll
    for (int s2=0;s2<2;++s2)
      #pragma unroll
      for (int cb=0;cb<2;++cb) bb[s2][cb] = nb[s2][cb];
    if (cc+1 < 72) LOADB2(cc+1, nb)
    const int tap = cc>>3, sg = cc&7;
    const u16* pA = sA + (l31 + tap)*YSTR + sg*32 + h*8;
    #pragma unroll
    for (int st=0; st<2; ++st){
      short8 a[2][2];
      #pragma unroll
      for (int rb=0; rb<2; ++rb)
        #pragma unroll
        for (int s2=0; s2<2; ++s2)
          a[rb][s2] = *(const short8*)(pA + (st*64 + rb*32)*YSTR + s2*16);
      #pragma unroll
      for (int rb=0; rb<2; ++rb){
        MFMA32(acc[st][rb][0], a[rb][0], bb[0][0]);
        MFMA32(acc[st][rb][0], a[rb][1], bb[1][0]);
        MFMA32(acc[st][rb][1], a[rb][0], bb[0][1]);
        MFMA32(acc[st][rb][1], a[rb][1], bb[1][1]);
      }
    }
  }

  asm volatile("s_nop 7\n\ts_nop 7\n\ts_nop 7" :: );

  #pragma unroll
  for (int st=0;st<2;++st)
    #pragma unroll
    for (int rb=0;rb<2;++rb)
      #pragma unroll
      for (int r=0;r<16;++r){
        float v0 = fmaxf(acc[st][rb][0][r] + bcol[0], 0.f);
        float v1 = fmaxf(acc[st][rb][1][r] + bcol[1], 0.f);
        float s = v0+v1, q = v0*v0+v1*v1;
        #pragma unroll
        for (int off=1; off<32; off<<=1){ s += __shfl_xor(s, off); q += __shfl_xor(q, off); }
        if (l31 == 0){ int row = st*64 + rb*32 + (r&3) + 8*(r>>2) + 4*h;
          sred[row*4+cg]=s; sred2[row*4+cg]=q; }
      }
  __syncthreads();
  if (tid < 128){
    float ss=0.f, qq=0.f;
    #pragma unroll
    for (int w2=0; w2<4; w2++){ ss += sred[tid*4+w2]; qq += sred2[tid*4+w2]; }
    float mean = ss * (1.f/FILT);
    float var  = qq * (1.f/FILT) - mean*mean;
    smean[tid] = mean;
    srstd[tid] = rsqrtf(fmaxf(var, 0.f) + EPS);
  }
  __syncthreads();

  #pragma unroll
  for (int st=0;st<2;++st)
    #pragma unroll
    for (int rb=0;rb<2;++rb)
      #pragma unroll
      for (int q=0;q<4;++q){
        const int rbase = st*64 + rb*32 + q*8 + 4*h;
        int p0v = pidT[rbase]; int fold = (p0v == pidT[rbase+3]);
        float mn0=smean[rbase+0],mn1=smean[rbase+1],mn2=smean[rbase+2],mn3=smean[rbase+3];
        float rs0=srstd[rbase+0],rs1=srstd[rbase+1],rs2=srstd[rbase+2],rs3=srstd[rbase+3];
        int pp = __shfl_xor(p0v, 32); int fp = __shfl_xor(fold, 32);
        #pragma unroll
        for (int cb=0;cb<2;++cb){
          int c = cg*64 + cb*32 + l31;
          float x0 = fmaxf(acc[st][rb][cb][q*4+0] + bcol[cb], 0.f);
          float x1 = fmaxf(acc[st][rb][cb][q*4+1] + bcol[cb], 0.f);
          float x2 = fmaxf(acc[st][rb][cb][q*4+2] + bcol[cb], 0.f);
          float x3 = fmaxf(acc[st][rb][cb][q*4+3] + bcol[cb], 0.f);
          float o0 = (x0-mn0)*rs0*gcol[cb]+btcol[cb];
          float o1 = (x1-mn1)*rs1*gcol[cb]+btcol[cb];
          float o2 = (x2-mn2)*rs2*gcol[cb]+btcol[cb];
          float o3 = (x3-mn3)*rs3*gcol[cb]+btcol[cb];
          float s4 = fold ? (o0+o1+o2+o3) : 0.f;
          float sp = __shfl_xor(s4, 32);
          float* basep = ps + (size_t)b*P_*FILT;
          if (fold){
            if (p0v < P_){
              if (fp && pp == p0v){ if (h == 0) atomicAdd(basep + (size_t)p0v*FILT + c, s4 + sp); }
              else atomicAdd(basep + (size_t)p0v*FILT + c, s4);
            }
          } else {
            int pj;
            pj = pidT[rbase+0]; if (pj < P_) atomicAdd(basep + (size_t)pj*FILT + c, o0);
            pj = pidT[rbase+1]; if (pj < P_) atomicAdd(basep + (size_t)pj*FILT + c, o1);
            pj = pidT[rbase+2]; if (pj < P_) atomicAdd(basep + (size_t)pj*FILT + c, o2);
            pj = pidT[rbase+3]; if (pj < P_) atomicAdd(basep + (size_t)pj*FILT + c, o3);
          }
        }
      }
}

// ---------------- word pooling + MLP: 8 words per block ----------------
#define WPB 8
__global__ __launch_bounds__(256) void word_k(
    const float* __restrict__ ps, const int* __restrict__ dur,
    const int* __restrict__ wcum, const int* __restrict__ wpl,
    const float* __restrict__ w1, const float* __restrict__ b1,
    const float* __restrict__ w2, const float* __restrict__ b2,
    float* __restrict__ wemb){
  int b = blockIdx.y, wg = blockIdx.x * WPB, tid = threadIdx.x;
  __shared__ float wvS[WPB][FILT];
  __shared__ float h1S[WPB][FILT];
  #pragma unroll
  for (int k=0;k<WPB;k++){
    int w = wg + k;
    int p1 = wcum[b*W_ + w]; int p0 = (w == 0) ? 0 : wcum[b*W_ + w - 1];
    if (p1 > P_) p1 = P_;
    int len = wpl[b*W_ + w];
    float a = 0.f;
    for (int p = p0; p < p1; ++p){
      int d = dur[b*P_ + p]; d = d < 1 ? 1 : d;
      a += ps[((size_t)(b*P_ + p))*FILT + tid] / (float)d;
    }
    wvS[k][tid] = a / (float)(len < 1 ? 1 : len);
  }
  __syncthreads();
  float acc[WPB];
  #pragma unroll
  for (int k=0;k<WPB;k++) acc[k] = b1[tid];
  for (int i=0;i<FILT;i++){
    float wcol = w1[i*FILT + tid];
    #pragma unroll
    for (int k=0;k<WPB;k++) acc[k] += wvS[k][i] * wcol;
  }
  #pragma unroll
  for (int k=0;k<WPB;k++) h1S[k][tid] = fmaxf(acc[k], 0.f);
  __syncthreads();
  int c = tid & 63, kq = tid >> 6;
  #pragma unroll
  for (int kk=kq; kk<WPB; kk+=4){
    float u = b2[c];
    for (int i=0;i<FILT;i++) u += h1S[kk][i] * w2[i*PDIM + c];
    wemb[((size_t)(b*W_ + wg + kk))*PDIM + c] = fmaxf(u, 0.f);
  }
}

// ---------------- expand words -> phones + mask (float4) ----------------
__global__ void expand_k(const float* __restrict__ wemb, const int* __restrict__ wid,
                         const unsigned char* __restrict__ mask, float* __restrict__ out){
  int idx = blockIdx.x * 256 + threadIdx.x;
  if (idx >= B_*P_*16) return;
  int q = idx & 15; int p = (idx >> 4) & 511; int bb = idx >> 13;
  int w = wid[bb*P_ + p];
  f32x4 v = *(const f32x4*)(wemb + ((size_t)(bb*W_ + w))*PDIM + q*4);
  if (mask[bb*P_ + p]) v = (f32x4){0.f,0.f,0.f,0.f};
  *(f32x4*)(out + (size_t)idx*4) = v;
}

extern "C" void kernel_launch(void* const* d_in, const int* in_sizes, int n_in,
                              void* d_out, int out_size, void* d_ws, size_t ws_size,
                              hipStream_t stream) {
  const unsigned char* mask = (const unsigned char*)d_in[0];
  const float* mels = (const float*)d_in[1];
  const int*   dur  = (const int*)d_in[3];
  const int*   wpl  = (const int*)d_in[4];
  const float* c1w  = (const float*)d_in[5];
  const float* c1b  = (const float*)d_in[6];
  const float* l1g  = (const float*)d_in[7];
  const float* l1b  = (const float*)d_in[8];
  const float* c2w  = (const float*)d_in[9];
  const float* c2b  = (const float*)d_in[10];
  const float* l2g  = (const float*)d_in[11];
  const float* l2b  = (const float*)d_in[12];
  const float* w1   = (const float*)d_in[13];
  const float* b1   = (const float*)d_in[14];
  const float* w2   = (const float*)d_in[15];
  const float* b2   = (const float*)d_in[16];

  char* ws = (char*)d_ws;
  size_t off = 0;
  auto alloc = [&](size_t bytes){ void* p = ws + off; off += (bytes + 255) & ~(size_t)255; return p; };
  u16* melsPad = (u16*)alloc((size_t)B_*TP8*MSTR*2 + 32768);
  u16* y1Pad   = (u16*)alloc((size_t)B_*TP8*YSTR*2 + 32768);
  u16* Wp1     = (u16*)alloc((size_t)KW*12*FILT*8*2);
  u16* Wp2     = (u16*)alloc((size_t)KW*32*FILT*8*2 + 32768);
  int* wcum    = (int*)alloc((size_t)B_*W_*4);
  int* pid     = (int*)alloc((size_t)B_*T_*4);
  int* wid     = (int*)alloc((size_t)B_*P_*4);
  float* psum  = (float*)alloc((size_t)B_*P_*FILT*4);
  float* wemb  = (float*)alloc((size_t)B_*W_*PDIM*4);

  hipMemsetAsync(psum, 0, (size_t)B_*P_*FILT*4, stream);
  pack_w<<<(KW*12*FILT + KW*32*FILT + 255)/256, 256, 0, stream>>>(c1w, c2w, Wp1, Wp2);
  prep_mels<<<(B_*TP8*13 + 255)/256, 256, 0, stream>>>(mels, melsPad);
  prep_seg<<<B_, 256, 0, stream>>>(dur, wpl, wcum, pid, wid, y1Pad);
  conv1_k<<<dim3(T_/128, B_), 256, 0, stream>>>(melsPad, Wp1, c1b, l1g, l1b, y1Pad);
  conv2_k<<<dim3(T_/128, B_), 256, 0, stream>>>(y1Pad, Wp2, c2b, l2g, l2b, pid, psum);
  word_k<<<dim3(W_/WPB, B_), 256, 0, stream>>>(psum, dur, wcum, wpl, w1, b1, w2, b2, wemb);
  expand_k<<<(B_*P_*16 + 255)/256, 256, 0, stream>>>(wemb, wid, mask, (float*)d_out);
}